// Round 4
// baseline (408.427 us; speedup 1.0000x reference)
//
#include <hip/hip_runtime.h>

// VoxelToPoint via fixed-capacity bucketing + multi-group LDS gather.
//
// Accounting model (R3 post-mortem): our kernels ~130us of the 408us
// total; ~280us is harness reset traffic (1GiB ws poison fill = 165us +
// out poison + dozens of tiny memsets, all inside the timed graph).
// Controllable levers left: gather (~100us vs 62us traffic floor),
// launch/drain count, scatter prologue.
//
// R7 combo (low-risk):
//  - ovf cleanup merged into gather (blocks 0..31 post-loop; out slots
//    disjoint from bucketed writes; data from prior kernel -> no sync).
//    Pipeline shrinks to zero -> scatter -> gather.
//  - scatter uses 2D grid (blockIdx.y = b): no runtime integer divide.
//  - scatter loads coords nontemporally: 4.8MB read-once stream, keep
//    L2 for counts atomics + record stores.
//
// gather5: one block per GRP=8 consecutive line-groups; 512B contiguous
// per channel row (compulsory-only vf fetch, 8x MLP); records (1KB)
// prefetched to LDS; NT vf loads / NT out stores.

#define DDIM 64
#define HDIM 64
#define WDIM 64
#define CCH 64
#define DHW (DDIM * HDIM * WDIM)          // 1<<18
#define GROUPS_PER_B 16384                 // DHW/16: one 64B line-group per 16 z-voxels
#define NGROUPS_SHIFT 14
#define CAP 32                             // bucket capacity; Poisson(6.1), P(>32)~1e-15
#define GRP 8                              // groups per gather block
#define ROWLEN (GRP * 16 + 17)             // 145 floats: 145%32=17 (odd) -> conflict-free

typedef __attribute__((ext_vector_type(4))) float f32x4;
typedef __attribute__((ext_vector_type(4))) int i32x4;

__global__ void zero_kernel(int* __restrict__ p, int n) {
  int i = blockIdx.x * blockDim.x + threadIdx.x;
  if (i < n) p[i] = 0;
}

__device__ __forceinline__ void decode_point_nt(const int* cp, bool& valid, int& idx) {
  int x = __builtin_nontemporal_load(cp + 0);
  int y = __builtin_nontemporal_load(cp + 1);
  int z = __builtin_nontemporal_load(cp + 2);
  valid = (x < DDIM) && (y < HDIM) && (z < WDIM);  // reference: upper bound only
  int xi = min(max(x, 0), DDIM - 1);
  int yi = min(max(y, 0), HDIM - 1);
  int zi = min(max(z, 0), WDIM - 1);
  idx = (xi * HDIM + yi) * WDIM + zi;
}

__device__ __forceinline__ void decode_point(const int* cp, bool& valid, int& idx) {
  int x = cp[0], y = cp[1], z = cp[2];
  valid = (x < DDIM) && (y < HDIM) && (z < WDIM);
  int xi = min(max(x, 0), DDIM - 1);
  int yi = min(max(y, 0), HDIM - 1);
  int zi = min(max(z, 0), WDIM - 1);
  idx = (xi * HDIM + yi) * WDIM + zi;
}

// records[g*CAP + pos] = pid | zoff<<19 | invalid<<23   (pid < 2^19)
// Grid: (ceil(N/256), B) -> b = blockIdx.y, no integer divide.
__global__ void scatter_kernel(const int* __restrict__ coords, int* __restrict__ counts,
                               int* __restrict__ records, int* __restrict__ ovf_count,
                               int* __restrict__ ovf_list, int N) {
  int i = blockIdx.x * blockDim.x + threadIdx.x;
  if (i >= N) return;
  int b = blockIdx.y;
  int p = b * N + i;
  bool valid; int idx;
  decode_point_nt(coords + (size_t)p * 3, valid, idx);
  int g = b * GROUPS_PER_B + (idx >> 4);
  int pos = atomicAdd(&counts[g], 1);
  if (pos < CAP) {
    records[g * CAP + pos] = p | ((idx & 15) << 19) | (valid ? 0 : (1 << 23));
  } else {
    int o = atomicAdd(ovf_count, 1);   // astronomically rare; correctness net
    ovf_list[o] = p;
  }
}

// One workgroup per GRP consecutive (b, line-group)s. Blocks 0..31 also
// drain the overflow list afterwards (out slots disjoint: a point is
// either bucketed or overflowed, never both).
__global__ __launch_bounds__(256) void gather5_kernel(
    const float* __restrict__ vf, const int* __restrict__ counts,
    const int* __restrict__ records, const int* __restrict__ coords,
    const int* __restrict__ ovf_count, const int* __restrict__ ovf_list,
    float* __restrict__ out, int N) {
  __shared__ float lds[CCH * ROWLEN];      // 37120 B
  __shared__ int s_rec[GRP * CAP];         // 1 KB
  __shared__ int s_cnt[GRP];
  int g0 = blockIdx.x * GRP;               // GRP divides GROUPS_PER_B: never straddles b
  int b = g0 >> NGROUPS_SHIFT;
  int group0 = g0 & (GROUPS_PER_B - 1);
  int t = threadIdx.x;

  // Prefetch records (1KB contiguous) + counts for all GRP groups.
  if (t < 64) {
    ((i32x4*)s_rec)[t] = ((const i32x4*)(records + (size_t)g0 * CAP))[t];
  }
  if (t < GRP) s_cnt[t] = counts[g0 + t];

  // Stage GRP*4KB: 64 channels x (GRP*16) floats, 512B contiguous per channel.
  {
    int ch = t >> 2;
    int sub = t & 3;
    const float* src = vf + ((size_t)(b * CCH + ch) << 18) + ((size_t)group0 << 4) + (sub << 2);
    float* dst = &lds[ch * ROWLEN + (sub << 2)];
#pragma unroll
    for (int i = 0; i < GRP; i++) {
      f32x4 v4 = __builtin_nontemporal_load((const f32x4*)(src + i * 16));
      dst[i * 16 + 0] = v4.x; dst[i * 16 + 1] = v4.y;
      dst[i * 16 + 2] = v4.z; dst[i * 16 + 3] = v4.w;
    }
  }
  __syncthreads();

  int ch = t & 63;
  int wv = t >> 6;                         // 4 waves split each group's points
#pragma unroll
  for (int i = 0; i < GRP; i++) {
    int cnt = min(s_cnt[i], CAP);
    for (int s = wv; s < cnt; s += 4) {
      int r = s_rec[i * CAP + s];          // LDS broadcast
      int pid = r & 0x7FFFF;
      int zoff = (r >> 19) & 15;
      float v = (r & (1 << 23)) ? 0.0f : lds[ch * ROWLEN + i * 16 + zoff];
      __builtin_nontemporal_store(v, &out[((size_t)pid << 6) + ch]);  // 256B coalesced
    }
  }

  // Overflow cleanup (normally n==0: one load, done). 32 blocks * 4 waves.
  if (blockIdx.x < 32) {
    int n = *ovf_count;
    if (n == 0) return;
    int w = ((blockIdx.x << 8) + t) >> 6;
    int lane = t & 63;
    for (int i = w; i < n; i += 128) {
      int p = ovf_list[i];
      int bb = p / N;
      bool valid; int idx;
      decode_point(coords + (size_t)p * 3, valid, idx);
      float v = valid ? vf[((size_t)(bb * CCH + lane) << 18) + idx] : 0.0f;
      out[((size_t)p << 6) + lane] = v;
    }
  }
}

// Fallback if workspace too small.
__global__ __launch_bounds__(256) void direct_kernel(const float* __restrict__ vf,
                                                     const int* __restrict__ coords,
                                                     float* __restrict__ out,
                                                     int B, int N) {
  int gid = blockIdx.x * blockDim.x + threadIdx.x;
  int point = gid >> 6;
  int lane = gid & 63;
  if (point >= B * N) return;
  int b = point / N;
  bool valid; int idx;
  decode_point(coords + (size_t)point * 3, valid, idx);
  float v = 0.0f;
  if (valid) v = vf[(size_t)(b * CCH + lane) * DHW + idx];
  out[(size_t)point * CCH + lane] = v;
}

extern "C" void kernel_launch(void* const* d_in, const int* in_sizes, int n_in,
                              void* d_out, int out_size, void* d_ws, size_t ws_size,
                              hipStream_t stream) {
  const float* vf = (const float*)d_in[0];
  const int* coords = (const int*)d_in[1];
  float* out = (float*)d_out;

  int B = in_sizes[0] / (CCH * DHW);  // 4
  int N = in_sizes[1] / (B * 3);      // 100000
  int total = B * N;

  int nbuckets = B * GROUPS_PER_B;                    // 65536
  size_t counts_ints = (size_t)nbuckets + 64;         // counts + ovf counter pad
  size_t rec_ints = (size_t)nbuckets * CAP;           // 2M ints = 8 MB
  size_t need = (counts_ints + rec_ints + (size_t)total) * sizeof(int);  // ~10.3 MB

  if (ws_size < need || total >= (1 << 19)) {
    int threads = total * 64;
    direct_kernel<<<(threads + 255) / 256, 256, 0, stream>>>(vf, coords, out, B, N);
    return;
  }

  int* counts = (int*)d_ws;
  int* ovf_count = counts + nbuckets;
  int* records = counts + counts_ints;
  int* ovf_list = records + rec_ints;

  zero_kernel<<<((int)counts_ints + 255) / 256, 256, 0, stream>>>(counts, (int)counts_ints);
  dim3 sgrid((N + 255) / 256, B);
  scatter_kernel<<<sgrid, 256, 0, stream>>>(coords, counts, records, ovf_count, ovf_list, N);
  gather5_kernel<<<nbuckets / GRP, 256, 0, stream>>>(vf, counts, records, coords,
                                                     ovf_count, ovf_list, out, N);
}

// Round 5
// 397.416 us; speedup vs baseline: 1.0277x; 1.0277x over previous
//
#include <hip/hip_runtime.h>

// VoxelToPoint via fixed-capacity bucketing + multi-group LDS gather.
//
// Accounting model (R3/R4 post-mortem): our kernels ~125-130us of the
// ~408us total; ~280us is harness reset traffic (1GiB ws poison fill =
// 163us @82% peak + out poison + tiny memsets, inside the timed window).
// R8 targets the two remaining mechanisms:
//  - gather6: 512-thread blocks (8 waves) x GRP=8 groups. LDS 38.2KB ->
//    4 blocks/CU -> 32/32 waves resident (was 16/32). Stage indexing
//    ch=t>>3,sub=t&7: each wave instruction reads 8 channels x 128B FULL
//    lines (was 16 x 64B). Inner loop: wave w owns group w (one setup,
//    ~6 iters, s_rec broadcast preserved). ovf cleanup merged (blocks<32).
//  - scatter: LDS repack of coords -- 3 contiguous NT dword loads/thread
//    (perfectly coalesced), decode from LDS (3l%32 = 2-way alias, free).
//    2D grid (blockIdx.y=b), no integer divide.
// Pipeline: zero(260KB) -> scatter -> gather6.

#define DDIM 64
#define HDIM 64
#define WDIM 64
#define CCH 64
#define DHW (DDIM * HDIM * WDIM)          // 1<<18
#define GROUPS_PER_B 16384                 // DHW/16: one 64B line-group per 16 z-voxels
#define NGROUPS_SHIFT 14
#define CAP 32                             // bucket capacity; Poisson(6.1), P(>32)~1e-15
#define GRP 8                              // groups per gather block
#define ROWLEN (GRP * 16 + 17)             // 145 floats: 145%32=17 (odd) -> conflict-free

typedef __attribute__((ext_vector_type(4))) float f32x4;
typedef __attribute__((ext_vector_type(4))) int i32x4;

__global__ void zero_kernel(int* __restrict__ p, int n) {
  int i = blockIdx.x * blockDim.x + threadIdx.x;
  if (i < n) p[i] = 0;
}

__device__ __forceinline__ void decode_xyz(int x, int y, int z, bool& valid, int& idx) {
  valid = (x < DDIM) && (y < HDIM) && (z < WDIM);  // reference: upper bound only
  int xi = min(max(x, 0), DDIM - 1);
  int yi = min(max(y, 0), HDIM - 1);
  int zi = min(max(z, 0), WDIM - 1);
  idx = (xi * HDIM + yi) * WDIM + zi;
}

__device__ __forceinline__ void decode_point(const int* cp, bool& valid, int& idx) {
  decode_xyz(cp[0], cp[1], cp[2], valid, idx);
}

// records[g*CAP + pos] = pid | zoff<<19 | invalid<<23   (pid < 2^19)
// Grid: (ceil(N/256), B). Coords repacked through LDS for coalescing.
__global__ __launch_bounds__(256) void scatter_kernel(
    const int* __restrict__ coords, int* __restrict__ counts,
    int* __restrict__ records, int* __restrict__ ovf_count,
    int* __restrict__ ovf_list, int N) {
  __shared__ int sc[256 * 3];
  int t = threadIdx.x;
  int b = blockIdx.y;
  int i0 = blockIdx.x * 256;
  int npts = min(256, N - i0);
  int base = (b * N + i0) * 3;
  int lim = npts * 3;
  for (int j = t; j < lim; j += 256)
    sc[j] = __builtin_nontemporal_load(&coords[base + j]);
  __syncthreads();
  if (t >= npts) return;
  int p = b * N + i0 + t;
  bool valid; int idx;
  decode_xyz(sc[t * 3 + 0], sc[t * 3 + 1], sc[t * 3 + 2], valid, idx);
  int g = b * GROUPS_PER_B + (idx >> 4);
  int pos = atomicAdd(&counts[g], 1);
  if (pos < CAP) {
    records[g * CAP + pos] = p | ((idx & 15) << 19) | (valid ? 0 : (1 << 23));
  } else {
    int o = atomicAdd(ovf_count, 1);   // astronomically rare; correctness net
    ovf_list[o] = p;
  }
}

// One 512-thread workgroup per GRP=8 consecutive (b, line-group)s.
// 8 waves: wave w owns group w in the read-out loop. Blocks 0..31 also
// drain the overflow list (out slots disjoint from bucketed writes).
__global__ __launch_bounds__(512) void gather6_kernel(
    const float* __restrict__ vf, const int* __restrict__ counts,
    const int* __restrict__ records, const int* __restrict__ coords,
    const int* __restrict__ ovf_count, const int* __restrict__ ovf_list,
    float* __restrict__ out, int N) {
  __shared__ float lds[CCH * ROWLEN];      // 37120 B
  __shared__ int s_rec[GRP * CAP];         // 1 KB
  __shared__ int s_cnt[GRP];
  int g0 = blockIdx.x * GRP;               // GRP divides GROUPS_PER_B: never straddles b
  int b = g0 >> NGROUPS_SHIFT;
  int group0 = g0 & (GROUPS_PER_B - 1);
  int t = threadIdx.x;

  // Prefetch records (1KB contiguous) + counts for all GRP groups.
  if (t < 64) {
    ((i32x4*)s_rec)[t] = ((const i32x4*)(records + (size_t)g0 * CAP))[t];
  }
  if (t < GRP) s_cnt[t] = counts[g0 + t];

  // Stage GRP*4KB: 64 channels x 128 floats (512B) per channel row.
  // ch=t>>3, sub=t&7: one wave instruction = 8 channels x 128B full lines.
  {
    int ch = t >> 3;
    int sub = t & 7;
    const float* src = vf + ((size_t)(b * CCH + ch) << 18) + ((size_t)group0 << 4) + (sub << 2);
    float* dst = &lds[ch * ROWLEN + (sub << 2)];
#pragma unroll
    for (int i = 0; i < 4; i++) {
      f32x4 v4 = __builtin_nontemporal_load((const f32x4*)(src + i * 32));
      dst[i * 32 + 0] = v4.x; dst[i * 32 + 1] = v4.y;
      dst[i * 32 + 2] = v4.z; dst[i * 32 + 3] = v4.w;
    }
  }
  __syncthreads();

  int ch = t & 63;
  int wv = t >> 6;                         // wave w owns group w
  {
    int cnt = min(s_cnt[wv], CAP);
    const int rbase = wv * CAP;
    for (int s = 0; s < cnt; s++) {
      int r = s_rec[rbase + s];            // LDS broadcast (uniform per wave)
      int pid = r & 0x7FFFF;
      int zoff = (r >> 19) & 15;
      float v = (r & (1 << 23)) ? 0.0f : lds[ch * ROWLEN + (wv << 4) + zoff];
      __builtin_nontemporal_store(v, &out[((size_t)pid << 6) + ch]);  // 256B coalesced
    }
  }

  // Overflow cleanup (normally n==0: one load, done). 32 blocks * 8 waves.
  if (blockIdx.x < 32) {
    int n = *ovf_count;
    if (n == 0) return;
    int w = ((blockIdx.x << 9) + t) >> 6;  // global wave id, 256 waves
    int lane = t & 63;
    for (int i = w; i < n; i += 256) {
      int p = ovf_list[i];
      int bb = p / N;
      bool valid; int idx;
      decode_point(coords + (size_t)p * 3, valid, idx);
      float v = valid ? vf[((size_t)(bb * CCH + lane) << 18) + idx] : 0.0f;
      out[((size_t)p << 6) + lane] = v;
    }
  }
}

// Fallback if workspace too small.
__global__ __launch_bounds__(256) void direct_kernel(const float* __restrict__ vf,
                                                     const int* __restrict__ coords,
                                                     float* __restrict__ out,
                                                     int B, int N) {
  int gid = blockIdx.x * blockDim.x + threadIdx.x;
  int point = gid >> 6;
  int lane = gid & 63;
  if (point >= B * N) return;
  int b = point / N;
  bool valid; int idx;
  decode_point(coords + (size_t)point * 3, valid, idx);
  float v = 0.0f;
  if (valid) v = vf[(size_t)(b * CCH + lane) * DHW + idx];
  out[(size_t)point * CCH + lane] = v;
}

extern "C" void kernel_launch(void* const* d_in, const int* in_sizes, int n_in,
                              void* d_out, int out_size, void* d_ws, size_t ws_size,
                              hipStream_t stream) {
  const float* vf = (const float*)d_in[0];
  const int* coords = (const int*)d_in[1];
  float* out = (float*)d_out;

  int B = in_sizes[0] / (CCH * DHW);  // 4
  int N = in_sizes[1] / (B * 3);      // 100000
  int total = B * N;

  int nbuckets = B * GROUPS_PER_B;                    // 65536
  size_t counts_ints = (size_t)nbuckets + 64;         // counts + ovf counter pad
  size_t rec_ints = (size_t)nbuckets * CAP;           // 2M ints = 8 MB
  size_t need = (counts_ints + rec_ints + (size_t)total) * sizeof(int);  // ~10.3 MB

  if (ws_size < need || total >= (1 << 19)) {
    int threads = total * 64;
    direct_kernel<<<(threads + 255) / 256, 256, 0, stream>>>(vf, coords, out, B, N);
    return;
  }

  int* counts = (int*)d_ws;
  int* ovf_count = counts + nbuckets;
  int* records = counts + counts_ints;
  int* ovf_list = records + rec_ints;

  zero_kernel<<<((int)counts_ints + 255) / 256, 256, 0, stream>>>(counts, (int)counts_ints);
  dim3 sgrid((N + 255) / 256, B);
  scatter_kernel<<<sgrid, 256, 0, stream>>>(coords, counts, records, ovf_count, ovf_list, N);
  gather6_kernel<<<nbuckets / GRP, 512, 0, stream>>>(vf, counts, records, coords,
                                                     ovf_count, ovf_list, out, N);
}

// Round 6
// 395.656 us; speedup vs baseline: 1.0323x; 1.0044x over previous
//
#include <hip/hip_runtime.h>

// VoxelToPoint via fixed-capacity bucketing + multi-group LDS gather.
//
// Accounting model (R3-R5 post-mortems): our kernels ~105-115us of the
// ~397us total; ~280us is harness reset traffic (1GiB ws poison fill =
// 163us @82% peak, out poison, dozens of tiny memsets) inside the timed
// window. Controllable floor ~62-70us (268MB vf + 102MB out + 16MB rec
// RT + 5MB coords @ 6.3TB/s).
//
// R9 (gather7): GRP=16 groups per block, 1024 threads (16 waves).
//  - LDS 72KB -> 2 blocks/CU x 16 waves = 32/32 waves resident (same max
//    occupancy as R8) but HALF the blocks (4096): per-block prefetch,
//    barrier and readout-ramp overhead amortized over 2x bytes.
//  - 1KB sequential stream per channel row (was 512B): better DRAM page
//    locality for the 268MB compulsory vf read.
//  - ROWLEN=273 (273%32=17, gcd 1): readout 2-way bank alias (free);
//    stage write = 4ch x 16sub per wave = exactly 2 lanes/bank (free).
//  - wave w owns group w in readout (16 waves = GRP); s_rec broadcast.
//  - ovf cleanup merged (blocks<32); NT loads on all read-once streams.
// Pipeline: zero(260KB) -> scatter(LDS-repacked coords) -> gather7.

#define DDIM 64
#define HDIM 64
#define WDIM 64
#define CCH 64
#define DHW (DDIM * HDIM * WDIM)          // 1<<18
#define GROUPS_PER_B 16384                 // DHW/16: one 64B line-group per 16 z-voxels
#define NGROUPS_SHIFT 14
#define CAP 32                             // bucket capacity; Poisson(6.1), P(>32)~1e-15
#define GRP 16                             // groups per gather block
#define ROWLEN (GRP * 16 + 17)             // 273 floats: 273%32=17 (odd) -> conflict-free

typedef __attribute__((ext_vector_type(4))) float f32x4;
typedef __attribute__((ext_vector_type(4))) int i32x4;

__global__ void zero_kernel(int* __restrict__ p, int n) {
  int i = blockIdx.x * blockDim.x + threadIdx.x;
  if (i < n) p[i] = 0;
}

__device__ __forceinline__ void decode_xyz(int x, int y, int z, bool& valid, int& idx) {
  valid = (x < DDIM) && (y < HDIM) && (z < WDIM);  // reference: upper bound only
  int xi = min(max(x, 0), DDIM - 1);
  int yi = min(max(y, 0), HDIM - 1);
  int zi = min(max(z, 0), WDIM - 1);
  idx = (xi * HDIM + yi) * WDIM + zi;
}

__device__ __forceinline__ void decode_point(const int* cp, bool& valid, int& idx) {
  decode_xyz(cp[0], cp[1], cp[2], valid, idx);
}

// records[g*CAP + pos] = pid | zoff<<19 | invalid<<23   (pid < 2^19)
// Grid: (ceil(N/256), B). Coords repacked through LDS for coalescing.
__global__ __launch_bounds__(256) void scatter_kernel(
    const int* __restrict__ coords, int* __restrict__ counts,
    int* __restrict__ records, int* __restrict__ ovf_count,
    int* __restrict__ ovf_list, int N) {
  __shared__ int sc[256 * 3];
  int t = threadIdx.x;
  int b = blockIdx.y;
  int i0 = blockIdx.x * 256;
  int npts = min(256, N - i0);
  int base = (b * N + i0) * 3;
  int lim = npts * 3;
  for (int j = t; j < lim; j += 256)
    sc[j] = __builtin_nontemporal_load(&coords[base + j]);
  __syncthreads();
  if (t >= npts) return;
  int p = b * N + i0 + t;
  bool valid; int idx;
  decode_xyz(sc[t * 3 + 0], sc[t * 3 + 1], sc[t * 3 + 2], valid, idx);
  int g = b * GROUPS_PER_B + (idx >> 4);
  int pos = atomicAdd(&counts[g], 1);
  if (pos < CAP) {
    records[g * CAP + pos] = p | ((idx & 15) << 19) | (valid ? 0 : (1 << 23));
  } else {
    int o = atomicAdd(ovf_count, 1);   // astronomically rare; correctness net
    ovf_list[o] = p;
  }
}

// One 1024-thread workgroup per GRP=16 consecutive (b, line-group)s.
// 16 waves: wave w owns group w in the read-out loop. Blocks 0..31 also
// drain the overflow list (out slots disjoint from bucketed writes).
__global__ __launch_bounds__(1024) void gather7_kernel(
    const float* __restrict__ vf, const int* __restrict__ counts,
    const int* __restrict__ records, const int* __restrict__ coords,
    const int* __restrict__ ovf_count, const int* __restrict__ ovf_list,
    float* __restrict__ out, int N) {
  __shared__ float lds[CCH * ROWLEN];      // 69888 B
  __shared__ int s_rec[GRP * CAP];         // 2 KB
  __shared__ int s_cnt[GRP];
  int g0 = blockIdx.x * GRP;               // GRP divides GROUPS_PER_B: never straddles b
  int b = g0 >> NGROUPS_SHIFT;
  int group0 = g0 & (GROUPS_PER_B - 1);
  int t = threadIdx.x;

  // Prefetch records (2KB contiguous) + counts for all GRP groups.
  if (t < 128) {
    ((i32x4*)s_rec)[t] =
        __builtin_nontemporal_load(((const i32x4*)(records + (size_t)g0 * CAP)) + t);
  }
  if (t < GRP) s_cnt[t] = counts[g0 + t];

  // Stage GRP*4KB: 64 channels x 256 floats (1KB) per channel row.
  // ch=t>>4, sub=t&15: one wave instruction = 4 channels x 256B spans.
  {
    int ch = t >> 4;
    int sub = t & 15;
    const float* src = vf + ((size_t)(b * CCH + ch) << 18) + ((size_t)group0 << 4) + (sub << 2);
    float* dst = &lds[ch * ROWLEN + (sub << 2)];
#pragma unroll
    for (int i = 0; i < 4; i++) {
      f32x4 v4 = __builtin_nontemporal_load((const f32x4*)(src + i * 64));
      dst[i * 64 + 0] = v4.x; dst[i * 64 + 1] = v4.y;
      dst[i * 64 + 2] = v4.z; dst[i * 64 + 3] = v4.w;
    }
  }
  __syncthreads();

  int ch = t & 63;
  int wv = t >> 6;                         // wave w owns group w (16 waves = GRP)
  {
    int cnt = min(s_cnt[wv], CAP);
    const int rbase = wv * CAP;
    for (int s = 0; s < cnt; s++) {
      int r = s_rec[rbase + s];            // LDS broadcast (uniform per wave)
      int pid = r & 0x7FFFF;
      int zoff = (r >> 19) & 15;
      float v = (r & (1 << 23)) ? 0.0f : lds[ch * ROWLEN + (wv << 4) + zoff];
      __builtin_nontemporal_store(v, &out[((size_t)pid << 6) + ch]);  // 256B coalesced
    }
  }

  // Overflow cleanup (normally n==0: one load, done). 32 blocks * 16 waves.
  if (blockIdx.x < 32) {
    int n = *ovf_count;
    if (n == 0) return;
    int w = ((blockIdx.x << 10) + t) >> 6;  // global wave id, 512 waves
    int lane = t & 63;
    for (int i = w; i < n; i += 512) {
      int p = ovf_list[i];
      int bb = p / N;
      bool valid; int idx;
      decode_point(coords + (size_t)p * 3, valid, idx);
      float v = valid ? vf[((size_t)(bb * CCH + lane) << 18) + idx] : 0.0f;
      out[((size_t)p << 6) + lane] = v;
    }
  }
}

// Fallback if workspace too small.
__global__ __launch_bounds__(256) void direct_kernel(const float* __restrict__ vf,
                                                     const int* __restrict__ coords,
                                                     float* __restrict__ out,
                                                     int B, int N) {
  int gid = blockIdx.x * blockDim.x + threadIdx.x;
  int point = gid >> 6;
  int lane = gid & 63;
  if (point >= B * N) return;
  int b = point / N;
  bool valid; int idx;
  decode_point(coords + (size_t)point * 3, valid, idx);
  float v = 0.0f;
  if (valid) v = vf[(size_t)(b * CCH + lane) * DHW + idx];
  out[(size_t)point * CCH + lane] = v;
}

extern "C" void kernel_launch(void* const* d_in, const int* in_sizes, int n_in,
                              void* d_out, int out_size, void* d_ws, size_t ws_size,
                              hipStream_t stream) {
  const float* vf = (const float*)d_in[0];
  const int* coords = (const int*)d_in[1];
  float* out = (float*)d_out;

  int B = in_sizes[0] / (CCH * DHW);  // 4
  int N = in_sizes[1] / (B * 3);      // 100000
  int total = B * N;

  int nbuckets = B * GROUPS_PER_B;                    // 65536
  size_t counts_ints = (size_t)nbuckets + 64;         // counts + ovf counter pad
  size_t rec_ints = (size_t)nbuckets * CAP;           // 2M ints = 8 MB
  size_t need = (counts_ints + rec_ints + (size_t)total) * sizeof(int);  // ~10.3 MB

  if (ws_size < need || total >= (1 << 19)) {
    int threads = total * 64;
    direct_kernel<<<(threads + 255) / 256, 256, 0, stream>>>(vf, coords, out, B, N);
    return;
  }

  int* counts = (int*)d_ws;
  int* ovf_count = counts + nbuckets;
  int* records = counts + counts_ints;
  int* ovf_list = records + rec_ints;

  zero_kernel<<<((int)counts_ints + 255) / 256, 256, 0, stream>>>(counts, (int)counts_ints);
  dim3 sgrid((N + 255) / 256, B);
  scatter_kernel<<<sgrid, 256, 0, stream>>>(coords, counts, records, ovf_count, ovf_list, N);
  gather7_kernel<<<nbuckets / GRP, 1024, 0, stream>>>(vf, counts, records, coords,
                                                      ovf_count, ovf_list, out, N);
}